// Round 5
// baseline (458.456 us; speedup 1.0000x reference)
//
#include <hip/hip_runtime.h>
#include <hip/hip_bf16.h>
#include <cstdint>
#include <cstddef>

typedef unsigned short u16;
typedef __bf16 bf16x8 __attribute__((ext_vector_type(8)));
typedef float f32x4 __attribute__((ext_vector_type(4)));
typedef unsigned short u16x4 __attribute__((ext_vector_type(4)));

#define AS1(p) ((__attribute__((address_space(1))) void*)(p))
#define AS3(p) ((__attribute__((address_space(3))) void*)(p))

__device__ __forceinline__ float bf2f(u16 u) {
  unsigned v = ((unsigned)u) << 16; float f; __builtin_memcpy(&f, &v, 4); return f;
}
__device__ __forceinline__ u16 f2bf(float f) {
  unsigned u; __builtin_memcpy(&u, &f, 4);
  u += 0x7FFFu + ((u >> 16) & 1u);   // RNE
  return (u16)(u >> 16);
}

// ---------------- fp32 -> bf16 convert (plain) ----------------
__global__ __launch_bounds__(256) void convert_kernel(const float* __restrict__ src,
                                                      u16* __restrict__ dst, int n4) {
  int i = blockIdx.x * blockDim.x + threadIdx.x;
  int stride = gridDim.x * blockDim.x;
  for (; i < n4; i += stride) {
    float4 v = ((const float4*)src)[i];
    u16x4 o;
    o.x = f2bf(v.x); o.y = f2bf(v.y); o.z = f2bf(v.z); o.w = f2bf(v.w);
    ((u16x4*)dst)[i] = o;
  }
}

// ---------------- fp32 -> bf16 hi + lo split ----------------
__global__ __launch_bounds__(256) void convert_split_kernel(const float* __restrict__ src,
                                                            u16* __restrict__ hi,
                                                            u16* __restrict__ lo, int n4) {
  int i = blockIdx.x * blockDim.x + threadIdx.x;
  int stride = gridDim.x * blockDim.x;
  for (; i < n4; i += stride) {
    float4 v = ((const float4*)src)[i];
    u16x4 oh, ol;
    oh.x = f2bf(v.x); ol.x = f2bf(v.x - bf2f(oh.x));
    oh.y = f2bf(v.y); ol.y = f2bf(v.y - bf2f(oh.y));
    oh.z = f2bf(v.z); ol.z = f2bf(v.z - bf2f(oh.z));
    oh.w = f2bf(v.w); ol.w = f2bf(v.w - bf2f(oh.w));
    ((u16x4*)hi)[i] = oh;
    ((u16x4*)lo)[i] = ol;
  }
}

// ---------------- transpose + split: x[b,n,c] fp32 -> Xb[b,n,c] bf16, XT{hi,lo}[b,c,n] ----------------
__global__ __launch_bounds__(256) void transpose_split_kernel(const float* __restrict__ x,
                                                              u16* __restrict__ Xb,
                                                              u16* __restrict__ XThi,
                                                              u16* __restrict__ XTlo) {
  __shared__ u16 lhi[64 * 68];
  __shared__ u16 llo[64 * 68];
  const int t  = threadIdx.x;
  const int nT = blockIdx.x, cT = blockIdx.y, b = blockIdx.z;
  const size_t xbase = ((size_t)b * 4096 + nT * 64) * 1024 + cT * 64;
  const int c4 = (t & 15) * 4;
  const int r0 = t >> 4;
#pragma unroll
  for (int j = 0; j < 4; ++j) {
    int r = r0 + j * 16;
    float4 v = *(const float4*)(x + xbase + (size_t)r * 1024 + c4);
    u16x4 hi;
    hi.x = f2bf(v.x); hi.y = f2bf(v.y); hi.z = f2bf(v.z); hi.w = f2bf(v.w);
    *(u16x4*)(Xb + xbase + (size_t)r * 1024 + c4) = hi;
    u16 lo[4];
    lo[0] = f2bf(v.x - bf2f(hi.x)); lo[1] = f2bf(v.y - bf2f(hi.y));
    lo[2] = f2bf(v.z - bf2f(hi.z)); lo[3] = f2bf(v.w - bf2f(hi.w));
    u16 hia[4] = { hi.x, hi.y, hi.z, hi.w };
#pragma unroll
    for (int i = 0; i < 4; ++i) {
      lhi[(c4 + i) * 68 + r] = hia[i];
      llo[(c4 + i) * 68 + r] = lo[i];
    }
  }
  __syncthreads();
  const int c  = t >> 2;
  const int n0 = (t & 3) * 16;
  const size_t tbase = ((size_t)b * 1024 + cT * 64 + c) * 4096 + nT * 64 + n0;
#pragma unroll
  for (int q = 0; q < 4; ++q) {
    *(u16x4*)(XThi + tbase + q * 4) = *(const u16x4*)(lhi + c * 68 + n0 + q * 4);
    *(u16x4*)(XTlo + tbase + q * 4) = *(const u16x4*)(llo + c * 68 + n0 + q * 4);
  }
}

// ---------------- m97-style GEMM: C[M,N] = A[M,K] * B[N,K]^T (single bf16) ----------------
template<bool OUT_BF16, bool HAS_BIAS>
__global__ __launch_bounds__(256) void gemm_bt(const u16* __restrict__ A,
                                               const u16* __restrict__ B,
                                               void* __restrict__ Cv,
                                               const float* __restrict__ bias,
                                               int M, int N, int K) {
  __shared__ __align__(16) u16 lA[128 * 32];
  __shared__ __align__(16) u16 lB[128 * 32];
  const int tid  = threadIdx.x;
  const int lane = tid & 63;
  const int wave = tid >> 6;
  const int rowTile = blockIdx.x * 128;
  const int colTile = blockIdx.y * 128;
  const int wr = (wave >> 1) * 64;
  const int wc = (wave & 1) * 64;

  f32x4 acc[4][4] = {};
  const int m  = lane & 15;
  const int ko = (lane >> 4) * 8;

  for (int kt = 0; kt < K; kt += 32) {
#pragma unroll
    for (int i = 0; i < 2; ++i) {
      int idx = i * 256 + tid;
      int row = idx >> 2;
      int kc  = (idx & 3) * 8;
      int ldsOff = (i * 256 + (tid & 192)) * 16;
      __builtin_amdgcn_global_load_lds(AS1(A + (size_t)(rowTile + row) * K + kt + kc),
                                       AS3((char*)lA + ldsOff), 16, 0, 0);
      __builtin_amdgcn_global_load_lds(AS1(B + (size_t)(colTile + row) * K + kt + kc),
                                       AS3((char*)lB + ldsOff), 16, 0, 0);
    }
    __syncthreads();
    bf16x8 af[4], bfr[4];
#pragma unroll
    for (int rb = 0; rb < 4; ++rb)
      af[rb] = *(const bf16x8*)(lA + (wr + rb * 16 + m) * 32 + ko);
#pragma unroll
    for (int cb = 0; cb < 4; ++cb)
      bfr[cb] = *(const bf16x8*)(lB + (wc + cb * 16 + m) * 32 + ko);
#pragma unroll
    for (int rb = 0; rb < 4; ++rb)
#pragma unroll
      for (int cb = 0; cb < 4; ++cb)
        acc[rb][cb] = __builtin_amdgcn_mfma_f32_16x16x32_bf16(af[rb], bfr[cb], acc[rb][cb], 0, 0, 0);
    __syncthreads();
  }

  const int crow0 = rowTile + wr + (lane >> 4) * 4;
  const int ccol0 = colTile + wc + (lane & 15);
#pragma unroll
  for (int rb = 0; rb < 4; ++rb) {
#pragma unroll
    for (int cb = 0; cb < 4; ++cb) {
      int col = ccol0 + cb * 16;
      float bv = HAS_BIAS ? bias[col] : 0.f;
#pragma unroll
      for (int r = 0; r < 4; ++r) {
        int row = crow0 + rb * 16 + r;
        float v = acc[rb][cb][r] + bv;
        if (OUT_BF16) ((u16*)Cv)[(size_t)row * N + col] = f2bf(v);
        else          ((float*)Cv)[(size_t)row * N + col] = v;
      }
    }
  }
}

// ---------------- batched GEMM: Y_b = V_b @ M_b^T + bias (fp32 out) ----------------
__global__ __launch_bounds__(256) void gemm_vm(const u16* __restrict__ V,
                                               const u16* __restrict__ Mb,
                                               float* __restrict__ Y,
                                               const float* __restrict__ bias) {
  __shared__ __align__(16) u16 lA[128 * 32];
  __shared__ __align__(16) u16 lB[128 * 32];
  const int tid  = threadIdx.x;
  const int lane = tid & 63;
  const int wave = tid >> 6;
  const int rowTile = blockIdx.x * 128;
  const int colTile = blockIdx.y * 128;
  const int bz = blockIdx.z;
  const u16* A = V + ((size_t)bz << 22);
  const u16* B = Mb + ((size_t)bz << 20);
  float* C = Y + ((size_t)bz << 22);
  const int wr = (wave >> 1) * 64;
  const int wc = (wave & 1) * 64;

  f32x4 acc[4][4] = {};
  const int m  = lane & 15;
  const int ko = (lane >> 4) * 8;

  for (int kt = 0; kt < 1024; kt += 32) {
#pragma unroll
    for (int i = 0; i < 2; ++i) {
      int idx = i * 256 + tid;
      int row = idx >> 2;
      int kc  = (idx & 3) * 8;
      int ldsOff = (i * 256 + (tid & 192)) * 16;
      __builtin_amdgcn_global_load_lds(AS1(A + (size_t)(rowTile + row) * 1024 + kt + kc),
                                       AS3((char*)lA + ldsOff), 16, 0, 0);
      __builtin_amdgcn_global_load_lds(AS1(B + (size_t)(colTile + row) * 1024 + kt + kc),
                                       AS3((char*)lB + ldsOff), 16, 0, 0);
    }
    __syncthreads();
    bf16x8 af[4], bfr[4];
#pragma unroll
    for (int rb = 0; rb < 4; ++rb)
      af[rb] = *(const bf16x8*)(lA + (wr + rb * 16 + m) * 32 + ko);
#pragma unroll
    for (int cb = 0; cb < 4; ++cb)
      bfr[cb] = *(const bf16x8*)(lB + (wc + cb * 16 + m) * 32 + ko);
#pragma unroll
    for (int rb = 0; rb < 4; ++rb)
#pragma unroll
      for (int cb = 0; cb < 4; ++cb)
        acc[rb][cb] = __builtin_amdgcn_mfma_f32_16x16x32_bf16(af[rb], bfr[cb], acc[rb][cb], 0, 0, 0);
    __syncthreads();
  }

  const int crow0 = rowTile + wr + (lane >> 4) * 4;
  const int ccol0 = colTile + wc + (lane & 15);
#pragma unroll
  for (int rb = 0; rb < 4; ++rb)
#pragma unroll
    for (int cb = 0; cb < 4; ++cb) {
      int col = ccol0 + cb * 16;
      float bv = bias[col];
#pragma unroll
      for (int r = 0; r < 4; ++r)
        C[(size_t)(crow0 + rb * 16 + r) * 1024 + col] = acc[rb][cb][r] + bv;
    }
}

// ---------------- balanced symmetric Gram with atomic flush ----------------
// 144 upper-tri 128-tiles (4 b x 36), each 128 BK32-iters -> 18432 units.
// 512 blocks x 36 units each. Block spans <=2 tiles (never a batch). Flush per
// segment with fp32 atomicAdd into zeroed Gpart[b] (full 1024x1024).
__global__ __launch_bounds__(256) void gemm_gram(const u16* __restrict__ XThi,
                                                 const u16* __restrict__ XTlo,
                                                 float* __restrict__ Gpart) {
  __shared__ __align__(16) u16 lAh[128 * 32];
  __shared__ __align__(16) u16 lAl[128 * 32];
  __shared__ __align__(16) u16 lBh[128 * 32];
  __shared__ __align__(16) u16 lBl[128 * 32];
  const int tid  = threadIdx.x;
  const int lane = tid & 63;
  const int wave = tid >> 6;
  const int wr = (wave >> 1) * 64;
  const int wc = (wave & 1) * 64;
  const int m  = lane & 15;
  const int ko = (lane >> 4) * 8;

  const int u0 = blockIdx.x * 36;
  const int b  = u0 / 4608;
  int ub   = u0 - b * 4608;
  int tile = ub >> 7;
  int koff = ub & 127;

  const u16* Ahp = XThi + ((size_t)b << 22);
  const u16* Alp = XTlo + ((size_t)b << 22);
  float* out = Gpart + ((size_t)b << 20);

  int remaining = 36;
  for (int seg = 0; seg < 2 && remaining > 0; ++seg) {
    int niter = min(remaining, 128 - koff);
    // tile -> (rt, ct), rt <= ct
    int t = tile, rt = 0;
    while (t >= 8 - rt) { t -= 8 - rt; ++rt; }
    int ct = rt + t;
    const int rowTile = rt * 128, colTile = ct * 128;

    f32x4 acc[4][4] = {};
    const int kend = (koff + niter) * 32;
    for (int kt = koff * 32; kt < kend; kt += 32) {
#pragma unroll
      for (int i = 0; i < 2; ++i) {
        int idx = i * 256 + tid;
        int row = idx >> 2;
        int kc  = (idx & 3) * 8;
        int ldsOff = (i * 256 + (tid & 192)) * 16;
        size_t aoff = (size_t)(rowTile + row) * 4096 + kt + kc;
        size_t boff = (size_t)(colTile + row) * 4096 + kt + kc;
        __builtin_amdgcn_global_load_lds(AS1(Ahp + aoff), AS3((char*)lAh + ldsOff), 16, 0, 0);
        __builtin_amdgcn_global_load_lds(AS1(Alp + aoff), AS3((char*)lAl + ldsOff), 16, 0, 0);
        __builtin_amdgcn_global_load_lds(AS1(Ahp + boff), AS3((char*)lBh + ldsOff), 16, 0, 0);
        __builtin_amdgcn_global_load_lds(AS1(Alp + boff), AS3((char*)lBl + ldsOff), 16, 0, 0);
      }
      __syncthreads();
      bf16x8 ah[4], al[4], bh[4], bl[4];
#pragma unroll
      for (int rb = 0; rb < 4; ++rb) {
        ah[rb] = *(const bf16x8*)(lAh + (wr + rb * 16 + m) * 32 + ko);
        al[rb] = *(const bf16x8*)(lAl + (wr + rb * 16 + m) * 32 + ko);
      }
#pragma unroll
      for (int cb = 0; cb < 4; ++cb) {
        bh[cb] = *(const bf16x8*)(lBh + (wc + cb * 16 + m) * 32 + ko);
        bl[cb] = *(const bf16x8*)(lBl + (wc + cb * 16 + m) * 32 + ko);
      }
#pragma unroll
      for (int rb = 0; rb < 4; ++rb)
#pragma unroll
        for (int cb = 0; cb < 4; ++cb) {
          acc[rb][cb] = __builtin_amdgcn_mfma_f32_16x16x32_bf16(ah[rb], bh[cb], acc[rb][cb], 0, 0, 0);
          acc[rb][cb] = __builtin_amdgcn_mfma_f32_16x16x32_bf16(ah[rb], bl[cb], acc[rb][cb], 0, 0, 0);
          acc[rb][cb] = __builtin_amdgcn_mfma_f32_16x16x32_bf16(al[rb], bh[cb], acc[rb][cb], 0, 0, 0);
        }
      __syncthreads();
    }

    // flush segment
    const int crow0 = rowTile + wr + (lane >> 4) * 4;
    const int ccol0 = colTile + wc + (lane & 15);
#pragma unroll
    for (int rb = 0; rb < 4; ++rb)
#pragma unroll
      for (int cb = 0; cb < 4; ++cb)
#pragma unroll
        for (int r = 0; r < 4; ++r)
          atomicAdd(&out[(size_t)(crow0 + rb * 16 + r) * 1024 + ccol0 + cb * 16],
                    acc[rb][cb][r]);

    remaining -= niter;
    tile += 1;
    koff = 0;
  }
}

// ---------------- reduce: mirror lower from upper, split to bf16 hi/lo ----------------
__global__ __launch_bounds__(256) void gram_reduce_split(const float* __restrict__ Gp,
                                                         u16* __restrict__ Ghi,
                                                         u16* __restrict__ Glo) {
  const int rt = blockIdx.x, ct = blockIdx.y, b = blockIdx.z;  // 64x64 tiles
  const float* P = Gp + ((size_t)b << 20);
  const bool mirror = (rt >> 1) > (ct >> 1);   // strictly-lower 128-tile: read transpose
  __shared__ float lT[64 * 68];
  const int t = threadIdx.x;
  const int r = t >> 2;
  const int c16 = (t & 3) * 16;

  if (mirror) {
    const size_t bb = (size_t)(ct * 64 + r) * 1024 + rt * 64 + c16;
#pragma unroll
    for (int q = 0; q < 4; ++q)
      *(float4*)(lT + r * 68 + c16 + q * 4) = *(const float4*)(P + bb + q * 4);
    __syncthreads();
  }

  const size_t ab = (size_t)(rt * 64 + r) * 1024 + ct * 64 + c16;
  const size_t ob = ((size_t)b << 20) + ab;
#pragma unroll
  for (int q = 0; q < 4; ++q) {
    float g[4];
    if (mirror) {
#pragma unroll
      for (int i = 0; i < 4; ++i) g[i] = lT[(c16 + q * 4 + i) * 68 + r];
    } else {
      float4 v = *(const float4*)(P + ab + q * 4);
      g[0] = v.x; g[1] = v.y; g[2] = v.z; g[3] = v.w;
    }
    u16x4 oh, ol;
    oh.x = f2bf(g[0]); ol.x = f2bf(g[0] - bf2f(oh.x));
    oh.y = f2bf(g[1]); ol.y = f2bf(g[1] - bf2f(oh.y));
    oh.z = f2bf(g[2]); ol.z = f2bf(g[2] - bf2f(oh.z));
    oh.w = f2bf(g[3]); ol.w = f2bf(g[3] - bf2f(oh.w));
    *(u16x4*)(Ghi + ob + q * 4) = oh;
    *(u16x4*)(Glo + ob + q * 4) = ol;
  }
}

// ---------------- T' = Wq * G^T (G symmetric) per batch, split x3, split-bf16 out ----------------
__global__ __launch_bounds__(256) void gemm_tprime(const u16* __restrict__ Wqh,
                                                   const u16* __restrict__ Wql,
                                                   const u16* __restrict__ Ghi,
                                                   const u16* __restrict__ Glo,
                                                   u16* __restrict__ Tph,
                                                   u16* __restrict__ Tpl) {
  __shared__ __align__(16) u16 lAh[128 * 32];
  __shared__ __align__(16) u16 lAl[128 * 32];
  __shared__ __align__(16) u16 lBh[128 * 32];
  __shared__ __align__(16) u16 lBl[128 * 32];
  const int tid  = threadIdx.x;
  const int lane = tid & 63;
  const int wave = tid >> 6;
  const int rowTile = blockIdx.x * 128;
  const int colTile = blockIdx.y * 128;
  const size_t zoff = (size_t)blockIdx.z << 20;
  const int wr = (wave >> 1) * 64;
  const int wc = (wave & 1) * 64;

  f32x4 acc[4][4] = {};
  const int m  = lane & 15;
  const int ko = (lane >> 4) * 8;

  for (int kt = 0; kt < 1024; kt += 32) {
#pragma unroll
    for (int i = 0; i < 2; ++i) {
      int idx = i * 256 + tid;
      int row = idx >> 2;
      int kc  = (idx & 3) * 8;
      int ldsOff = (i * 256 + (tid & 192)) * 16;
      size_t aoff = (size_t)(rowTile + row) * 1024 + kt + kc;
      size_t boff = zoff + (size_t)(colTile + row) * 1024 + kt + kc;
      __builtin_amdgcn_global_load_lds(AS1(Wqh + aoff), AS3((char*)lAh + ldsOff), 16, 0, 0);
      __builtin_amdgcn_global_load_lds(AS1(Wql + aoff), AS3((char*)lAl + ldsOff), 16, 0, 0);
      __builtin_amdgcn_global_load_lds(AS1(Ghi + boff), AS3((char*)lBh + ldsOff), 16, 0, 0);
      __builtin_amdgcn_global_load_lds(AS1(Glo + boff), AS3((char*)lBl + ldsOff), 16, 0, 0);
    }
    __syncthreads();
    bf16x8 ah[4], al[4], bh[4], bl[4];
#pragma unroll
    for (int rb = 0; rb < 4; ++rb) {
      ah[rb] = *(const bf16x8*)(lAh + (wr + rb * 16 + m) * 32 + ko);
      al[rb] = *(const bf16x8*)(lAl + (wr + rb * 16 + m) * 32 + ko);
    }
#pragma unroll
    for (int cb = 0; cb < 4; ++cb) {
      bh[cb] = *(const bf16x8*)(lBh + (wc + cb * 16 + m) * 32 + ko);
      bl[cb] = *(const bf16x8*)(lBl + (wc + cb * 16 + m) * 32 + ko);
    }
#pragma unroll
    for (int rb = 0; rb < 4; ++rb)
#pragma unroll
      for (int cb = 0; cb < 4; ++cb) {
        acc[rb][cb] = __builtin_amdgcn_mfma_f32_16x16x32_bf16(ah[rb], bh[cb], acc[rb][cb], 0, 0, 0);
        acc[rb][cb] = __builtin_amdgcn_mfma_f32_16x16x32_bf16(ah[rb], bl[cb], acc[rb][cb], 0, 0, 0);
        acc[rb][cb] = __builtin_amdgcn_mfma_f32_16x16x32_bf16(al[rb], bh[cb], acc[rb][cb], 0, 0, 0);
      }
    __syncthreads();
  }

  const int crow0 = rowTile + wr + (lane >> 4) * 4;
  const int ccol0 = colTile + wc + (lane & 15);
#pragma unroll
  for (int rb = 0; rb < 4; ++rb)
#pragma unroll
    for (int cb = 0; cb < 4; ++cb)
#pragma unroll
      for (int r = 0; r < 4; ++r) {
        float v = acc[rb][cb][r];
        u16 hi = f2bf(v);
        u16 lo = f2bf(v - bf2f(hi));
        size_t off = zoff + (size_t)(crow0 + rb * 16 + r) * 1024 + ccol0 + cb * 16;
        Tph[off] = hi;
        Tpl[off] = lo;
      }
}

// ---------------- fused S + softmax -> attn^T (bf16) ----------------
__global__ __launch_bounds__(256) void s_softmax_kernel(const u16* __restrict__ Wqh,
                                                        const u16* __restrict__ Wql,
                                                        const u16* __restrict__ Tph,
                                                        const u16* __restrict__ Tpl,
                                                        const float* __restrict__ alpha,
                                                        u16* __restrict__ attnT) {
  const int h = blockIdx.x, b = blockIdx.y;
  const int tid = threadIdx.x, lane = tid & 63, wave = tid >> 6;
  __shared__ __align__(16) u16 lAh[64 * 32];
  __shared__ __align__(16) u16 lAl[64 * 32];
  __shared__ __align__(16) u16 lBh[64 * 32];
  __shared__ __align__(16) u16 lBl[64 * 32];

  const size_t aBase = (size_t)(1024 + h * 64) * 1024;
  const size_t bBase = ((size_t)b << 20) + (size_t)(h * 64) * 1024;

  f32x4 acc[4] = {};
  const int m  = lane & 15;
  const int ko = (lane >> 4) * 8;
  const int srow = tid >> 2;
  const int skc  = (tid & 3) * 8;
  const int ldsOff = (tid & 192) * 16;

  for (int kt = 0; kt < 1024; kt += 32) {
    __builtin_amdgcn_global_load_lds(AS1(Wqh + aBase + (size_t)srow * 1024 + kt + skc),
                                     AS3((char*)lAh + ldsOff), 16, 0, 0);
    __builtin_amdgcn_global_load_lds(AS1(Wql + aBase + (size_t)srow * 1024 + kt + skc),
                                     AS3((char*)lAl + ldsOff), 16, 0, 0);
    __builtin_amdgcn_global_load_lds(AS1(Tph + bBase + (size_t)srow * 1024 + kt + skc),
                                     AS3((char*)lBh + ldsOff), 16, 0, 0);
    __builtin_amdgcn_global_load_lds(AS1(Tpl + bBase + (size_t)srow * 1024 + kt + skc),
                                     AS3((char*)lBl + ldsOff), 16, 0, 0);
    __syncthreads();
    bf16x8 ah = *(const bf16x8*)(lAh + (wave * 16 + m) * 32 + ko);
    bf16x8 al = *(const bf16x8*)(lAl + (wave * 16 + m) * 32 + ko);
#pragma unroll
    for (int cb = 0; cb < 4; ++cb) {
      bf16x8 bh = *(const bf16x8*)(lBh + (cb * 16 + m) * 32 + ko);
      bf16x8 bl = *(const bf16x8*)(lBl + (cb * 16 + m) * 32 + ko);
      acc[cb] = __builtin_amdgcn_mfma_f32_16x16x32_bf16(ah, bh, acc[cb], 0, 0, 0);
      acc[cb] = __builtin_amdgcn_mfma_f32_16x16x32_bf16(ah, bl, acc[cb], 0, 0, 0);
      acc[cb] = __builtin_amdgcn_mfma_f32_16x16x32_bf16(al, bh, acc[cb], 0, 0, 0);
    }
    __syncthreads();
  }

  const float invA = 1.f / alpha[h];
  const int g = lane >> 4;
  const size_t obase = (size_t)(b * 16 + h) * 4096;
#pragma unroll
  for (int r = 0; r < 4; ++r) {
    int d = wave * 16 + g * 4 + r;
    float s[4];
#pragma unroll
    for (int cb = 0; cb < 4; ++cb) s[cb] = acc[cb][r] * invA;
    float mx = fmaxf(fmaxf(s[0], s[1]), fmaxf(s[2], s[3]));
#pragma unroll
    for (int o = 1; o < 16; o <<= 1) mx = fmaxf(mx, __shfl_xor(mx, o, 64));
    float e[4]; float sum = 0.f;
#pragma unroll
    for (int cb = 0; cb < 4; ++cb) { e[cb] = __expf(s[cb] - mx); sum += e[cb]; }
#pragma unroll
    for (int o = 1; o < 16; o <<= 1) sum += __shfl_xor(sum, o, 64);
    float inv = 1.f / sum;
    // transposed store: attnT[bh][e][d]
#pragma unroll
    for (int cb = 0; cb < 4; ++cb) {
      int e_idx = cb * 16 + (lane & 15);
      attnT[obase + (size_t)e_idx * 64 + d] = f2bf(e[cb] * inv);
    }
  }
}

// ---------------- M_b[o, h*64+e] = sum_d Wproj[o, h*64+d] * attn_bh[d,e] ----------------
__global__ __launch_bounds__(256) void m_build_kernel(const u16* __restrict__ Wpb,
                                                      const u16* __restrict__ attnT,
                                                      u16* __restrict__ Mb) {
  const int oT = blockIdx.x, h = blockIdx.y, b = blockIdx.z;
  const int tid = threadIdx.x, lane = tid & 63, wave = tid >> 6;
  __shared__ __align__(16) u16 lA[128 * 64];   // Wproj tile [o 128][d 64]
  __shared__ __align__(16) u16 lB[64 * 64];    // attnT [e 64][d 64]
  const int bh = b * 16 + h;
#pragma unroll
  for (int i = 0; i < 4; ++i) {
    int idx = i * 256 + tid;
    int row = idx >> 3;
    int kc  = (idx & 7) * 8;
    int ldsOff = (i * 256 + (tid & 192)) * 16;
    __builtin_amdgcn_global_load_lds(AS1(Wpb + (size_t)(oT * 128 + row) * 1024 + h * 64 + kc),
                                     AS3((char*)lA + ldsOff), 16, 0, 0);
  }
#pragma unroll
  for (int i = 0; i < 2; ++i) {
    int idx = i * 256 + tid;
    int ldsOff = (i * 256 + (tid & 192)) * 16;
    __builtin_amdgcn_global_load_lds(AS1(attnT + (size_t)bh * 4096 + idx * 8),
                                     AS3((char*)lB + ldsOff), 16, 0, 0);
  }
  __syncthreads();
  const int m  = lane & 15;
  const int ko = (lane >> 4) * 8;
  const int wr = wave * 32;
  f32x4 acc[2][4] = {};
#pragma unroll
  for (int ks = 0; ks < 2; ++ks) {
#pragma unroll
    for (int rb = 0; rb < 2; ++rb) {
      bf16x8 a = *(const bf16x8*)(lA + (wr + rb * 16 + m) * 64 + ks * 32 + ko);
#pragma unroll
      for (int cb = 0; cb < 4; ++cb) {
        bf16x8 bb = *(const bf16x8*)(lB + (cb * 16 + m) * 64 + ks * 32 + ko);
        acc[rb][cb] = __builtin_amdgcn_mfma_f32_16x16x32_bf16(a, bb, acc[rb][cb], 0, 0, 0);
      }
    }
  }
  u16* out = Mb + ((size_t)b << 20);
#pragma unroll
  for (int rb = 0; rb < 2; ++rb)
#pragma unroll
    for (int cb = 0; cb < 4; ++cb) {
      int col = h * 64 + cb * 16 + (lane & 15);
#pragma unroll
      for (int r = 0; r < 4; ++r) {
        int row = oT * 128 + wr + rb * 16 + (lane >> 4) * 4 + r;
        out[(size_t)row * 1024 + col] = f2bf(acc[rb][cb][r]);
      }
    }
}

extern "C" void kernel_launch(void* const* d_in, const int* in_sizes, int n_in,
                              void* d_out, int out_size, void* d_ws, size_t ws_size,
                              hipStream_t stream) {
  const float* x     = (const float*)d_in[0];
  const float* Wqkv  = (const float*)d_in[3];
  const float* Wproj = (const float*)d_in[4];
  const float* bproj = (const float*)d_in[5];
  const float* alpha = (const float*)d_in[6];

  char* ws = (char*)d_ws;
  // Region A (33.55 MB): Xb -> Gpart(16 MB) -> M(8 MB)
  u16*   Xb     = (u16*)ws;
  float* Gpart  = (float*)ws;
  u16*   Mb     = (u16*)ws;
  // Region B (33.55 MB): XThi -> attnT
  u16*   XThi   = (u16*)(ws + 33554432);
  u16*   attnTb = (u16*)(ws + 33554432);
  // Region C (33.55 MB): XTlo -> {Ghi, Glo, Tph, Tpl}
  u16*   XTlo  = (u16*)(ws + 67108864);
  u16*   Ghi   = (u16*)(ws + 67108864);
  u16*   Glo   = (u16*)(ws + 75497472);
  u16*   Tph   = (u16*)(ws + 83886080);
  u16*   Tpl   = (u16*)(ws + 92274688);
  u16*   Wqh   = (u16*)(ws + 100663296);
  u16*   Wql   = (u16*)(ws + 106954752);
  u16*   Vb    = (u16*)(ws + 113246208);
  u16*   Wpb   = (u16*)(ws + 146800640);   // end: 148.9 MB

  // 1. x -> Xb + XThi/XTlo
  transpose_split_kernel<<<dim3(64, 16, 4), 256, 0, stream>>>(x, Xb, XThi, XTlo);
  // 2. weight converts
  convert_split_kernel<<<256, 256, 0, stream>>>(Wqkv, Wqh, Wql, 3145728 / 4);
  convert_kernel<<<128, 256, 0, stream>>>(Wproj, Wpb, 1048576 / 4);
  // 3. V = X @ Wv^T
  gemm_bt<true, false><<<dim3(128, 8), 256, 0, stream>>>(
      Xb, Wqh + (size_t)2048 * 1024, Vb, nullptr, 16384, 1024, 1024);
  // 3b. zero Gpart (aliases Xb; stream-ordered after step 3)
  hipMemsetAsync(Gpart, 0, (size_t)4 * 1024 * 1024 * 4, stream);
  // 4. balanced symmetric Gram partials (atomic flush)
  gemm_gram<<<512, 256, 0, stream>>>(XThi, XTlo, Gpart);
  // 5. mirror + hi/lo split (overwrites XTlo region)
  gram_reduce_split<<<dim3(16, 16, 4), 256, 0, stream>>>(Gpart, Ghi, Glo);
  // 6. T' = Wq G
  gemm_tprime<<<dim3(8, 8, 4), 256, 0, stream>>>(Wqh, Wql, Ghi, Glo, Tph, Tpl);
  // 7. fused S + softmax -> attn^T (overwrites XThi region)
  s_softmax_kernel<<<dim3(16, 4), 256, 0, stream>>>(Wqh, Wql, Tph, Tpl, alpha, attnTb);
  // 8. M_b = blockdiag(Wproj_h @ attn_bh) (overwrites Gpart region)
  m_build_kernel<<<dim3(8, 16, 4), 256, 0, stream>>>(Wpb, attnTb, Mb);
  // 9. Y_b = V_b @ M_b^T + bproj (fp32 out)
  gemm_vm<<<dim3(32, 8, 4), 256, 0, stream>>>(Vb, Mb, (float*)d_out, bproj);
}

// Round 6
// 440.169 us; speedup vs baseline: 1.0415x; 1.0415x over previous
//
#include <hip/hip_runtime.h>
#include <hip/hip_bf16.h>
#include <cstdint>
#include <cstddef>

typedef unsigned short u16;
typedef __bf16 bf16x8 __attribute__((ext_vector_type(8)));
typedef float f32x4 __attribute__((ext_vector_type(4)));
typedef unsigned short u16x4 __attribute__((ext_vector_type(4)));

#define AS1(p) ((__attribute__((address_space(1))) void*)(p))
#define AS3(p) ((__attribute__((address_space(3))) void*)(p))

__device__ __forceinline__ float bf2f(u16 u) {
  unsigned v = ((unsigned)u) << 16; float f; __builtin_memcpy(&f, &v, 4); return f;
}
__device__ __forceinline__ u16 f2bf(float f) {
  unsigned u; __builtin_memcpy(&u, &f, 4);
  u += 0x7FFFu + ((u >> 16) & 1u);   // RNE
  return (u16)(u >> 16);
}

// ---------------- fp32 -> bf16 convert (plain) ----------------
__global__ __launch_bounds__(256) void convert_kernel(const float* __restrict__ src,
                                                      u16* __restrict__ dst, int n4) {
  int i = blockIdx.x * blockDim.x + threadIdx.x;
  int stride = gridDim.x * blockDim.x;
  for (; i < n4; i += stride) {
    float4 v = ((const float4*)src)[i];
    u16x4 o;
    o.x = f2bf(v.x); o.y = f2bf(v.y); o.z = f2bf(v.z); o.w = f2bf(v.w);
    ((u16x4*)dst)[i] = o;
  }
}

// ---------------- fp32 -> bf16 hi + lo split ----------------
__global__ __launch_bounds__(256) void convert_split_kernel(const float* __restrict__ src,
                                                            u16* __restrict__ hi,
                                                            u16* __restrict__ lo, int n4) {
  int i = blockIdx.x * blockDim.x + threadIdx.x;
  int stride = gridDim.x * blockDim.x;
  for (; i < n4; i += stride) {
    float4 v = ((const float4*)src)[i];
    u16x4 oh, ol;
    oh.x = f2bf(v.x); ol.x = f2bf(v.x - bf2f(oh.x));
    oh.y = f2bf(v.y); ol.y = f2bf(v.y - bf2f(oh.y));
    oh.z = f2bf(v.z); ol.z = f2bf(v.z - bf2f(oh.z));
    oh.w = f2bf(v.w); ol.w = f2bf(v.w - bf2f(oh.w));
    ((u16x4*)hi)[i] = oh;
    ((u16x4*)lo)[i] = ol;
  }
}

// ---------------- transpose + split: x[b,n,c] fp32 -> Xb[b,n,c] bf16, XT{hi,lo}[b,c,n] ----------------
__global__ __launch_bounds__(256) void transpose_split_kernel(const float* __restrict__ x,
                                                              u16* __restrict__ Xb,
                                                              u16* __restrict__ XThi,
                                                              u16* __restrict__ XTlo) {
  __shared__ u16 lhi[64 * 68];
  __shared__ u16 llo[64 * 68];
  const int t  = threadIdx.x;
  const int nT = blockIdx.x, cT = blockIdx.y, b = blockIdx.z;
  const size_t xbase = ((size_t)b * 4096 + nT * 64) * 1024 + cT * 64;
  const int c4 = (t & 15) * 4;
  const int r0 = t >> 4;
#pragma unroll
  for (int j = 0; j < 4; ++j) {
    int r = r0 + j * 16;
    float4 v = *(const float4*)(x + xbase + (size_t)r * 1024 + c4);
    u16x4 hi;
    hi.x = f2bf(v.x); hi.y = f2bf(v.y); hi.z = f2bf(v.z); hi.w = f2bf(v.w);
    *(u16x4*)(Xb + xbase + (size_t)r * 1024 + c4) = hi;
    u16 lo[4];
    lo[0] = f2bf(v.x - bf2f(hi.x)); lo[1] = f2bf(v.y - bf2f(hi.y));
    lo[2] = f2bf(v.z - bf2f(hi.z)); lo[3] = f2bf(v.w - bf2f(hi.w));
    u16 hia[4] = { hi.x, hi.y, hi.z, hi.w };
#pragma unroll
    for (int i = 0; i < 4; ++i) {
      lhi[(c4 + i) * 68 + r] = hia[i];
      llo[(c4 + i) * 68 + r] = lo[i];
    }
  }
  __syncthreads();
  const int c  = t >> 2;
  const int n0 = (t & 3) * 16;
  const size_t tbase = ((size_t)b * 1024 + cT * 64 + c) * 4096 + nT * 64 + n0;
#pragma unroll
  for (int q = 0; q < 4; ++q) {
    *(u16x4*)(XThi + tbase + q * 4) = *(const u16x4*)(lhi + c * 68 + n0 + q * 4);
    *(u16x4*)(XTlo + tbase + q * 4) = *(const u16x4*)(llo + c * 68 + n0 + q * 4);
  }
}

// ---------------- m97-style GEMM: C[M,N] = A[M,K] * B[N,K]^T (single bf16) ----------------
template<bool OUT_BF16, bool HAS_BIAS>
__global__ __launch_bounds__(256) void gemm_bt(const u16* __restrict__ A,
                                               const u16* __restrict__ B,
                                               void* __restrict__ Cv,
                                               const float* __restrict__ bias,
                                               int M, int N, int K) {
  __shared__ __align__(16) u16 lA[128 * 32];
  __shared__ __align__(16) u16 lB[128 * 32];
  const int tid  = threadIdx.x;
  const int lane = tid & 63;
  const int wave = tid >> 6;
  const int rowTile = blockIdx.x * 128;
  const int colTile = blockIdx.y * 128;
  const int wr = (wave >> 1) * 64;
  const int wc = (wave & 1) * 64;

  f32x4 acc[4][4] = {};
  const int m  = lane & 15;
  const int ko = (lane >> 4) * 8;

  for (int kt = 0; kt < K; kt += 32) {
#pragma unroll
    for (int i = 0; i < 2; ++i) {
      int idx = i * 256 + tid;
      int row = idx >> 2;
      int kc  = (idx & 3) * 8;
      int ldsOff = (i * 256 + (tid & 192)) * 16;
      __builtin_amdgcn_global_load_lds(AS1(A + (size_t)(rowTile + row) * K + kt + kc),
                                       AS3((char*)lA + ldsOff), 16, 0, 0);
      __builtin_amdgcn_global_load_lds(AS1(B + (size_t)(colTile + row) * K + kt + kc),
                                       AS3((char*)lB + ldsOff), 16, 0, 0);
    }
    __syncthreads();
    bf16x8 af[4], bfr[4];
#pragma unroll
    for (int rb = 0; rb < 4; ++rb)
      af[rb] = *(const bf16x8*)(lA + (wr + rb * 16 + m) * 32 + ko);
#pragma unroll
    for (int cb = 0; cb < 4; ++cb)
      bfr[cb] = *(const bf16x8*)(lB + (wc + cb * 16 + m) * 32 + ko);
#pragma unroll
    for (int rb = 0; rb < 4; ++rb)
#pragma unroll
      for (int cb = 0; cb < 4; ++cb)
        acc[rb][cb] = __builtin_amdgcn_mfma_f32_16x16x32_bf16(af[rb], bfr[cb], acc[rb][cb], 0, 0, 0);
    __syncthreads();
  }

  const int crow0 = rowTile + wr + (lane >> 4) * 4;
  const int ccol0 = colTile + wc + (lane & 15);
#pragma unroll
  for (int rb = 0; rb < 4; ++rb) {
#pragma unroll
    for (int cb = 0; cb < 4; ++cb) {
      int col = ccol0 + cb * 16;
      float bv = HAS_BIAS ? bias[col] : 0.f;
#pragma unroll
      for (int r = 0; r < 4; ++r) {
        int row = crow0 + rb * 16 + r;
        float v = acc[rb][cb][r] + bv;
        if (OUT_BF16) ((u16*)Cv)[(size_t)row * N + col] = f2bf(v);
        else          ((float*)Cv)[(size_t)row * N + col] = v;
      }
    }
  }
}

// ---------------- batched GEMM: Y_b = V_b @ M_b^T + bias (fp32 out) ----------------
__global__ __launch_bounds__(256) void gemm_vm(const u16* __restrict__ V,
                                               const u16* __restrict__ Mb,
                                               float* __restrict__ Y,
                                               const float* __restrict__ bias) {
  __shared__ __align__(16) u16 lA[128 * 32];
  __shared__ __align__(16) u16 lB[128 * 32];
  const int tid  = threadIdx.x;
  const int lane = tid & 63;
  const int wave = tid >> 6;
  const int rowTile = blockIdx.x * 128;
  const int colTile = blockIdx.y * 128;
  const int bz = blockIdx.z;
  const u16* A = V + ((size_t)bz << 22);
  const u16* B = Mb + ((size_t)bz << 20);
  float* C = Y + ((size_t)bz << 22);
  const int wr = (wave >> 1) * 64;
  const int wc = (wave & 1) * 64;

  f32x4 acc[4][4] = {};
  const int m  = lane & 15;
  const int ko = (lane >> 4) * 8;

  for (int kt = 0; kt < 1024; kt += 32) {
#pragma unroll
    for (int i = 0; i < 2; ++i) {
      int idx = i * 256 + tid;
      int row = idx >> 2;
      int kc  = (idx & 3) * 8;
      int ldsOff = (i * 256 + (tid & 192)) * 16;
      __builtin_amdgcn_global_load_lds(AS1(A + (size_t)(rowTile + row) * 1024 + kt + kc),
                                       AS3((char*)lA + ldsOff), 16, 0, 0);
      __builtin_amdgcn_global_load_lds(AS1(B + (size_t)(colTile + row) * 1024 + kt + kc),
                                       AS3((char*)lB + ldsOff), 16, 0, 0);
    }
    __syncthreads();
    bf16x8 af[4], bfr[4];
#pragma unroll
    for (int rb = 0; rb < 4; ++rb)
      af[rb] = *(const bf16x8*)(lA + (wr + rb * 16 + m) * 32 + ko);
#pragma unroll
    for (int cb = 0; cb < 4; ++cb)
      bfr[cb] = *(const bf16x8*)(lB + (wc + cb * 16 + m) * 32 + ko);
#pragma unroll
    for (int rb = 0; rb < 4; ++rb)
#pragma unroll
      for (int cb = 0; cb < 4; ++cb)
        acc[rb][cb] = __builtin_amdgcn_mfma_f32_16x16x32_bf16(af[rb], bfr[cb], acc[rb][cb], 0, 0, 0);
    __syncthreads();
  }

  const int crow0 = rowTile + wr + (lane >> 4) * 4;
  const int ccol0 = colTile + wc + (lane & 15);
#pragma unroll
  for (int rb = 0; rb < 4; ++rb)
#pragma unroll
    for (int cb = 0; cb < 4; ++cb) {
      int col = ccol0 + cb * 16;
      float bv = bias[col];
#pragma unroll
      for (int r = 0; r < 4; ++r)
        C[(size_t)(crow0 + rb * 16 + r) * 1024 + col] = acc[rb][cb][r] + bv;
    }
}

// ---------------- uniform symmetric Gram, slice stores (atomics only on diag) ----------------
// 576 jobs: (36 upper-tri tiles x 4 K-quarters) x 4 batches, all K=1024.
// Off-diag: kq<2 -> plain store quarter at (rt,ct) slice kq&1; kq>=2 -> plain store the
// swapped-orientation quarter at (ct,rt) slice kq&1 (== transpose of needed quarter).
// Diag: all kq atomicAdd into slice kq&1 at (rt,rt) (pre-zeroed) -> s0=q0+q2, s1=q1+q3.
// Reduce: G(upper) = s0+s1 (+ transpose(s0+s1 at mirror) for off-diag-128).
__global__ __launch_bounds__(256) void gemm_gram(const u16* __restrict__ XThi,
                                                 const u16* __restrict__ XTlo,
                                                 float* __restrict__ Gpart) {
  __shared__ __align__(16) u16 lAh[128 * 32];
  __shared__ __align__(16) u16 lAl[128 * 32];
  __shared__ __align__(16) u16 lBh[128 * 32];
  __shared__ __align__(16) u16 lBl[128 * 32];
  const int tid  = threadIdx.x;
  const int lane = tid & 63;
  const int wave = tid >> 6;
  const int wr = (wave >> 1) * 64;
  const int wc = (wave & 1) * 64;
  const int m  = lane & 15;
  const int ko = (lane >> 4) * 8;

  const int jx = blockIdx.x;          // 0..143: tile*4 + kq (kq adjacent for L2 reuse)
  const int b  = blockIdx.y;
  const int tile = jx >> 2, kq = jx & 3;
  int t = tile, rt = 0;
  while (t >= 8 - rt) { t -= 8 - rt; ++rt; }
  const int ct = rt + t;
  const bool diag = (rt == ct);
  int rT = rt, cT = ct;
  if (!diag && kq >= 2) { rT = ct; cT = rt; }
  const int slice = kq & 1;
  const int rowTile = rT * 128, colTile = cT * 128;
  const int k0 = kq * 1024;

  const u16* Ahp = XThi + ((size_t)b << 22);
  const u16* Alp = XTlo + ((size_t)b << 22);

  f32x4 acc[4][4] = {};
  for (int kt = k0; kt < k0 + 1024; kt += 32) {
#pragma unroll
    for (int i = 0; i < 2; ++i) {
      int idx = i * 256 + tid;
      int row = idx >> 2;
      int kc  = (idx & 3) * 8;
      int ldsOff = (i * 256 + (tid & 192)) * 16;
      size_t aoff = (size_t)(rowTile + row) * 4096 + kt + kc;
      size_t boff = (size_t)(colTile + row) * 4096 + kt + kc;
      __builtin_amdgcn_global_load_lds(AS1(Ahp + aoff), AS3((char*)lAh + ldsOff), 16, 0, 0);
      __builtin_amdgcn_global_load_lds(AS1(Alp + aoff), AS3((char*)lAl + ldsOff), 16, 0, 0);
      __builtin_amdgcn_global_load_lds(AS1(Ahp + boff), AS3((char*)lBh + ldsOff), 16, 0, 0);
      __builtin_amdgcn_global_load_lds(AS1(Alp + boff), AS3((char*)lBl + ldsOff), 16, 0, 0);
    }
    __syncthreads();
    bf16x8 ah[4], al[4], bh[4], bl[4];
#pragma unroll
    for (int rb = 0; rb < 4; ++rb) {
      ah[rb] = *(const bf16x8*)(lAh + (wr + rb * 16 + m) * 32 + ko);
      al[rb] = *(const bf16x8*)(lAl + (wr + rb * 16 + m) * 32 + ko);
    }
#pragma unroll
    for (int cb = 0; cb < 4; ++cb) {
      bh[cb] = *(const bf16x8*)(lBh + (wc + cb * 16 + m) * 32 + ko);
      bl[cb] = *(const bf16x8*)(lBl + (wc + cb * 16 + m) * 32 + ko);
    }
#pragma unroll
    for (int rb = 0; rb < 4; ++rb)
#pragma unroll
      for (int cb = 0; cb < 4; ++cb) {
        acc[rb][cb] = __builtin_amdgcn_mfma_f32_16x16x32_bf16(ah[rb], bh[cb], acc[rb][cb], 0, 0, 0);
        acc[rb][cb] = __builtin_amdgcn_mfma_f32_16x16x32_bf16(ah[rb], bl[cb], acc[rb][cb], 0, 0, 0);
        acc[rb][cb] = __builtin_amdgcn_mfma_f32_16x16x32_bf16(al[rb], bh[cb], acc[rb][cb], 0, 0, 0);
      }
    __syncthreads();
  }

  float* out = Gpart + ((size_t)(slice * 4 + b) << 20);
  const int crow0 = rowTile + wr + (lane >> 4) * 4;
  const int ccol0 = colTile + wc + (lane & 15);
  if (diag) {
#pragma unroll
    for (int rb = 0; rb < 4; ++rb)
#pragma unroll
      for (int cb = 0; cb < 4; ++cb)
#pragma unroll
        for (int r = 0; r < 4; ++r)
          atomicAdd(&out[(size_t)(crow0 + rb * 16 + r) * 1024 + ccol0 + cb * 16],
                    acc[rb][cb][r]);
  } else {
#pragma unroll
    for (int rb = 0; rb < 4; ++rb)
#pragma unroll
      for (int cb = 0; cb < 4; ++cb)
#pragma unroll
        for (int r = 0; r < 4; ++r)
          out[(size_t)(crow0 + rb * 16 + r) * 1024 + ccol0 + cb * 16] = acc[rb][cb][r];
  }
}

// ---------------- tiled reduce: G = s0+s1 (r,c) [+ (s0+s1)(c,r)^T if off-diag-128] ----------------
__global__ __launch_bounds__(256) void gram_reduce_split(const float* __restrict__ Gp,
                                                         u16* __restrict__ Ghi,
                                                         u16* __restrict__ Glo) {
  const int rt = blockIdx.x, ct = blockIdx.y, b = blockIdx.z;  // 64x64 tiles
  const bool diag128 = (rt >> 1) == (ct >> 1);
  const float* s0 = Gp + ((size_t)b << 20);
  const float* s1 = Gp + ((size_t)(4 + b) << 20);
  __shared__ float lT[64 * 68];
  const int t = threadIdx.x;
  const int r = t >> 2;
  const int c16 = (t & 3) * 16;

  if (!diag128) {
    const size_t bb = (size_t)(ct * 64 + r) * 1024 + rt * 64 + c16;
#pragma unroll
    for (int q = 0; q < 4; ++q) {
      float4 v0 = *(const float4*)(s0 + bb + q * 4);
      float4 v1 = *(const float4*)(s1 + bb + q * 4);
      float4 s = { v0.x + v1.x, v0.y + v1.y, v0.z + v1.z, v0.w + v1.w };
      *(float4*)(lT + r * 68 + c16 + q * 4) = s;
    }
    __syncthreads();
  }

  const size_t ab = (size_t)(rt * 64 + r) * 1024 + ct * 64 + c16;
  const size_t ob = ((size_t)b << 20) + ab;
#pragma unroll
  for (int q = 0; q < 4; ++q) {
    float4 v0 = *(const float4*)(s0 + ab + q * 4);
    float4 v1 = *(const float4*)(s1 + ab + q * 4);
    float g[4] = { v0.x + v1.x, v0.y + v1.y, v0.z + v1.z, v0.w + v1.w };
    if (!diag128) {
#pragma unroll
      for (int i = 0; i < 4; ++i) g[i] += lT[(c16 + q * 4 + i) * 68 + r];
    }
    u16x4 oh, ol;
    oh.x = f2bf(g[0]); ol.x = f2bf(g[0] - bf2f(oh.x));
    oh.y = f2bf(g[1]); ol.y = f2bf(g[1] - bf2f(oh.y));
    oh.z = f2bf(g[2]); ol.z = f2bf(g[2] - bf2f(oh.z));
    oh.w = f2bf(g[3]); ol.w = f2bf(g[3] - bf2f(oh.w));
    *(u16x4*)(Ghi + ob + q * 4) = oh;
    *(u16x4*)(Glo + ob + q * 4) = ol;
  }
}

// ---------------- T' = Wq * G^T (G symmetric) per batch, split x3, split-bf16 out ----------------
__global__ __launch_bounds__(256) void gemm_tprime(const u16* __restrict__ Wqh,
                                                   const u16* __restrict__ Wql,
                                                   const u16* __restrict__ Ghi,
                                                   const u16* __restrict__ Glo,
                                                   u16* __restrict__ Tph,
                                                   u16* __restrict__ Tpl) {
  __shared__ __align__(16) u16 lAh[128 * 32];
  __shared__ __align__(16) u16 lAl[128 * 32];
  __shared__ __align__(16) u16 lBh[128 * 32];
  __shared__ __align__(16) u16 lBl[128 * 32];
  const int tid  = threadIdx.x;
  const int lane = tid & 63;
  const int wave = tid >> 6;
  const int rowTile = blockIdx.x * 128;
  const int colTile = blockIdx.y * 128;
  const size_t zoff = (size_t)blockIdx.z << 20;
  const int wr = (wave >> 1) * 64;
  const int wc = (wave & 1) * 64;

  f32x4 acc[4][4] = {};
  const int m  = lane & 15;
  const int ko = (lane >> 4) * 8;

  for (int kt = 0; kt < 1024; kt += 32) {
#pragma unroll
    for (int i = 0; i < 2; ++i) {
      int idx = i * 256 + tid;
      int row = idx >> 2;
      int kc  = (idx & 3) * 8;
      int ldsOff = (i * 256 + (tid & 192)) * 16;
      size_t aoff = (size_t)(rowTile + row) * 1024 + kt + kc;
      size_t boff = zoff + (size_t)(colTile + row) * 1024 + kt + kc;
      __builtin_amdgcn_global_load_lds(AS1(Wqh + aoff), AS3((char*)lAh + ldsOff), 16, 0, 0);
      __builtin_amdgcn_global_load_lds(AS1(Wql + aoff), AS3((char*)lAl + ldsOff), 16, 0, 0);
      __builtin_amdgcn_global_load_lds(AS1(Ghi + boff), AS3((char*)lBh + ldsOff), 16, 0, 0);
      __builtin_amdgcn_global_load_lds(AS1(Glo + boff), AS3((char*)lBl + ldsOff), 16, 0, 0);
    }
    __syncthreads();
    bf16x8 ah[4], al[4], bh[4], bl[4];
#pragma unroll
    for (int rb = 0; rb < 4; ++rb) {
      ah[rb] = *(const bf16x8*)(lAh + (wr + rb * 16 + m) * 32 + ko);
      al[rb] = *(const bf16x8*)(lAl + (wr + rb * 16 + m) * 32 + ko);
    }
#pragma unroll
    for (int cb = 0; cb < 4; ++cb) {
      bh[cb] = *(const bf16x8*)(lBh + (wc + cb * 16 + m) * 32 + ko);
      bl[cb] = *(const bf16x8*)(lBl + (wc + cb * 16 + m) * 32 + ko);
    }
#pragma unroll
    for (int rb = 0; rb < 4; ++rb)
#pragma unroll
      for (int cb = 0; cb < 4; ++cb) {
        acc[rb][cb] = __builtin_amdgcn_mfma_f32_16x16x32_bf16(ah[rb], bh[cb], acc[rb][cb], 0, 0, 0);
        acc[rb][cb] = __builtin_amdgcn_mfma_f32_16x16x32_bf16(ah[rb], bl[cb], acc[rb][cb], 0, 0, 0);
        acc[rb][cb] = __builtin_amdgcn_mfma_f32_16x16x32_bf16(al[rb], bh[cb], acc[rb][cb], 0, 0, 0);
      }
    __syncthreads();
  }

  const int crow0 = rowTile + wr + (lane >> 4) * 4;
  const int ccol0 = colTile + wc + (lane & 15);
#pragma unroll
  for (int rb = 0; rb < 4; ++rb)
#pragma unroll
    for (int cb = 0; cb < 4; ++cb)
#pragma unroll
      for (int r = 0; r < 4; ++r) {
        float v = acc[rb][cb][r];
        u16 hi = f2bf(v);
        u16 lo = f2bf(v - bf2f(hi));
        size_t off = zoff + (size_t)(crow0 + rb * 16 + r) * 1024 + ccol0 + cb * 16;
        Tph[off] = hi;
        Tpl[off] = lo;
      }
}

// ---------------- fused S + softmax -> attn^T (bf16) ----------------
__global__ __launch_bounds__(256) void s_softmax_kernel(const u16* __restrict__ Wqh,
                                                        const u16* __restrict__ Wql,
                                                        const u16* __restrict__ Tph,
                                                        const u16* __restrict__ Tpl,
                                                        const float* __restrict__ alpha,
                                                        u16* __restrict__ attnT) {
  const int h = blockIdx.x, b = blockIdx.y;
  const int tid = threadIdx.x, lane = tid & 63, wave = tid >> 6;
  __shared__ __align__(16) u16 lAh[64 * 32];
  __shared__ __align__(16) u16 lAl[64 * 32];
  __shared__ __align__(16) u16 lBh[64 * 32];
  __shared__ __align__(16) u16 lBl[64 * 32];

  const size_t aBase = (size_t)(1024 + h * 64) * 1024;
  const size_t bBase = ((size_t)b << 20) + (size_t)(h * 64) * 1024;

  f32x4 acc[4] = {};
  const int m  = lane & 15;
  const int ko = (lane >> 4) * 8;
  const int srow = tid >> 2;
  const int skc  = (tid & 3) * 8;
  const int ldsOff = (tid & 192) * 16;

  for (int kt = 0; kt < 1024; kt += 32) {
    __builtin_amdgcn_global_load_lds(AS1(Wqh + aBase + (size_t)srow * 1024 + kt + skc),
                                     AS3((char*)lAh + ldsOff), 16, 0, 0);
    __builtin_amdgcn_global_load_lds(AS1(Wql + aBase + (size_t)srow * 1024 + kt + skc),
                                     AS3((char*)lAl + ldsOff), 16, 0, 0);
    __builtin_amdgcn_global_load_lds(AS1(Tph + bBase + (size_t)srow * 1024 + kt + skc),
                                     AS3((char*)lBh + ldsOff), 16, 0, 0);
    __builtin_amdgcn_global_load_lds(AS1(Tpl + bBase + (size_t)srow * 1024 + kt + skc),
                                     AS3((char*)lBl + ldsOff), 16, 0, 0);
    __syncthreads();
    bf16x8 ah = *(const bf16x8*)(lAh + (wave * 16 + m) * 32 + ko);
    bf16x8 al = *(const bf16x8*)(lAl + (wave * 16 + m) * 32 + ko);
#pragma unroll
    for (int cb = 0; cb < 4; ++cb) {
      bf16x8 bh = *(const bf16x8*)(lBh + (cb * 16 + m) * 32 + ko);
      bf16x8 bl = *(const bf16x8*)(lBl + (cb * 16 + m) * 32 + ko);
      acc[cb] = __builtin_amdgcn_mfma_f32_16x16x32_bf16(ah, bh, acc[cb], 0, 0, 0);
      acc[cb] = __builtin_amdgcn_mfma_f32_16x16x32_bf16(ah, bl, acc[cb], 0, 0, 0);
      acc[cb] = __builtin_amdgcn_mfma_f32_16x16x32_bf16(al, bh, acc[cb], 0, 0, 0);
    }
    __syncthreads();
  }

  const float invA = 1.f / alpha[h];
  const int g = lane >> 4;
  const size_t obase = (size_t)(b * 16 + h) * 4096;
#pragma unroll
  for (int r = 0; r < 4; ++r) {
    int d = wave * 16 + g * 4 + r;
    float s[4];
#pragma unroll
    for (int cb = 0; cb < 4; ++cb) s[cb] = acc[cb][r] * invA;
    float mx = fmaxf(fmaxf(s[0], s[1]), fmaxf(s[2], s[3]));
#pragma unroll
    for (int o = 1; o < 16; o <<= 1) mx = fmaxf(mx, __shfl_xor(mx, o, 64));
    float e[4]; float sum = 0.f;
#pragma unroll
    for (int cb = 0; cb < 4; ++cb) { e[cb] = __expf(s[cb] - mx); sum += e[cb]; }
#pragma unroll
    for (int o = 1; o < 16; o <<= 1) sum += __shfl_xor(sum, o, 64);
    float inv = 1.f / sum;
    // transposed store: attnT[bh][e][d]
#pragma unroll
    for (int cb = 0; cb < 4; ++cb) {
      int e_idx = cb * 16 + (lane & 15);
      attnT[obase + (size_t)e_idx * 64 + d] = f2bf(e[cb] * inv);
    }
  }
}

// ---------------- M_b[o, h*64+e] = sum_d Wproj[o, h*64+d] * attn_bh[d,e] ----------------
__global__ __launch_bounds__(256) void m_build_kernel(const u16* __restrict__ Wpb,
                                                      const u16* __restrict__ attnT,
                                                      u16* __restrict__ Mb) {
  const int oT = blockIdx.x, h = blockIdx.y, b = blockIdx.z;
  const int tid = threadIdx.x, lane = tid & 63, wave = tid >> 6;
  __shared__ __align__(16) u16 lA[128 * 64];   // Wproj tile [o 128][d 64]
  __shared__ __align__(16) u16 lB[64 * 64];    // attnT [e 64][d 64]
  const int bh = b * 16 + h;
#pragma unroll
  for (int i = 0; i < 4; ++i) {
    int idx = i * 256 + tid;
    int row = idx >> 3;
    int kc  = (idx & 7) * 8;
    int ldsOff = (i * 256 + (tid & 192)) * 16;
    __builtin_amdgcn_global_load_lds(AS1(Wpb + (size_t)(oT * 128 + row) * 1024 + h * 64 + kc),
                                     AS3((char*)lA + ldsOff), 16, 0, 0);
  }
#pragma unroll
  for (int i = 0; i < 2; ++i) {
    int idx = i * 256 + tid;
    int ldsOff = (i * 256 + (tid & 192)) * 16;
    __builtin_amdgcn_global_load_lds(AS1(attnT + (size_t)bh * 4096 + idx * 8),
                                     AS3((char*)lB + ldsOff), 16, 0, 0);
  }
  __syncthreads();
  const int m  = lane & 15;
  const int ko = (lane >> 4) * 8;
  const int wr = wave * 32;
  f32x4 acc[2][4] = {};
#pragma unroll
  for (int ks = 0; ks < 2; ++ks) {
#pragma unroll
    for (int rb = 0; rb < 2; ++rb) {
      bf16x8 a = *(const bf16x8*)(lA + (wr + rb * 16 + m) * 64 + ks * 32 + ko);
#pragma unroll
      for (int cb = 0; cb < 4; ++cb) {
        bf16x8 bb = *(const bf16x8*)(lB + (cb * 16 + m) * 64 + ks * 32 + ko);
        acc[rb][cb] = __builtin_amdgcn_mfma_f32_16x16x32_bf16(a, bb, acc[rb][cb], 0, 0, 0);
      }
    }
  }
  u16* out = Mb + ((size_t)b << 20);
#pragma unroll
  for (int rb = 0; rb < 2; ++rb)
#pragma unroll
    for (int cb = 0; cb < 4; ++cb) {
      int col = h * 64 + cb * 16 + (lane & 15);
#pragma unroll
      for (int r = 0; r < 4; ++r) {
        int row = oT * 128 + wr + rb * 16 + (lane >> 4) * 4 + r;
        out[(size_t)row * 1024 + col] = f2bf(acc[rb][cb][r]);
      }
    }
}

extern "C" void kernel_launch(void* const* d_in, const int* in_sizes, int n_in,
                              void* d_out, int out_size, void* d_ws, size_t ws_size,
                              hipStream_t stream) {
  const float* x     = (const float*)d_in[0];
  const float* Wqkv  = (const float*)d_in[3];
  const float* Wproj = (const float*)d_in[4];
  const float* bproj = (const float*)d_in[5];
  const float* alpha = (const float*)d_in[6];

  char* ws = (char*)d_ws;
  // Region A (33.55 MB): Xb -> Gpart(32 MB) -> Mb(8 MB)
  u16*   Xb     = (u16*)ws;
  float* Gpart  = (float*)ws;
  u16*   Mb     = (u16*)ws;
  // Region B (33.55 MB): XThi -> attnT
  u16*   XThi   = (u16*)(ws + 33554432);
  u16*   attnTb = (u16*)(ws + 33554432);
  // Region C (33.55 MB): XTlo -> {Ghi, Glo, Tph, Tpl}
  u16*   XTlo  = (u16*)(ws + 67108864);
  u16*   Ghi   = (u16*)(ws + 67108864);
  u16*   Glo   = (u16*)(ws + 75497472);
  u16*   Tph   = (u16*)(ws + 83886080);
  u16*   Tpl   = (u16*)(ws + 92274688);
  u16*   Wqh   = (u16*)(ws + 100663296);
  u16*   Wql   = (u16*)(ws + 106954752);
  u16*   Vb    = (u16*)(ws + 113246208);
  u16*   Wpb   = (u16*)(ws + 146800640);   // end: 148.9 MB

  // 1. x -> Xb + XThi/XTlo
  transpose_split_kernel<<<dim3(64, 16, 4), 256, 0, stream>>>(x, Xb, XThi, XTlo);
  // 2. weight converts
  convert_split_kernel<<<256, 256, 0, stream>>>(Wqkv, Wqh, Wql, 3145728 / 4);
  convert_kernel<<<128, 256, 0, stream>>>(Wproj, Wpb, 1048576 / 4);
  // 3. V = X @ Wv^T
  gemm_bt<true, false><<<dim3(128, 8), 256, 0, stream>>>(
      Xb, Wqh + (size_t)2048 * 1024, Vb, nullptr, 16384, 1024, 1024);
  // 3b. zero Gpart slices (aliases Xb; stream-ordered after step 3). Needed for diag atomics.
  hipMemsetAsync(Gpart, 0, (size_t)33554432, stream);
  // 4. uniform symmetric Gram partials (576 blocks, plain stores + diag atomics)
  gemm_gram<<<dim3(144, 4), 256, 0, stream>>>(XThi, XTlo, Gpart);
  // 5. transpose-add reduce + hi/lo split (overwrites XTlo region)
  gram_reduce_split<<<dim3(16, 16, 4), 256, 0, stream>>>(Gpart, Ghi, Glo);
  // 6. T' = Wq G
  gemm_tprime<<<dim3(8, 8, 4), 256, 0, stream>>>(Wqh, Wql, Ghi, Glo, Tph, Tpl);
  // 7. fused S + softmax -> attn^T (overwrites XThi region)
  s_softmax_kernel<<<dim3(16, 4), 256, 0, stream>>>(Wqh, Wql, Tph, Tpl, alpha, attnTb);
  // 8. M_b = blockdiag(Wproj_h @ attn_bh) (overwrites Gpart region)
  m_build_kernel<<<dim3(8, 16, 4), 256, 0, stream>>>(Wpb, attnTb, Mb);
  // 9. Y_b = V_b @ M_b^T + bproj (fp32 out)
  gemm_vm<<<dim3(32, 8, 4), 256, 0, stream>>>(Vb, Mb, (float*)d_out, bproj);
}